// Round 8
// baseline (8545.121 us; speedup 1.0000x reference)
//
#include <hip/hip_runtime.h>
#include <stdint.h>

#define B_SZ 64
#define T_SZ 2048
#define H_SZ 256
#define TH   (T_SZ * H_SZ)

typedef __attribute__((ext_vector_type(8))) short bf16x8_t;
typedef __attribute__((ext_vector_type(8))) _Float16 f16x8_t;
typedef __attribute__((ext_vector_type(4))) float f32x4_t;

static __device__ __forceinline__ unsigned short f2bf(float f){
  unsigned int u = __float_as_uint(f);
  return (unsigned short)((u + 0x7fffu + ((u >> 16) & 1u)) >> 16);
}
static __device__ __forceinline__ unsigned short f2h(float f){
  return __builtin_bit_cast(unsigned short, (_Float16)f);
}
static __device__ __forceinline__ float h2f(unsigned short h){
  return (float)__builtin_bit_cast(_Float16, h);
}
static __device__ __forceinline__ float sigmoidf_(float x){
  return 1.f / (1.f + __expf(-x));
}
static __device__ __forceinline__ float tanhf_(float x){
  float e = __expf(-2.f * fabsf(x));
  float t = (1.f - e) / (1.f + e);
  return copysignf(t, x);
}
// global -> LDS async DMA, 16B per lane; dest = wave-uniform base + lane*16
static __device__ __forceinline__ void stage16(const void* g, void* l){
  __builtin_amdgcn_global_load_lds(
      (const __attribute__((address_space(1))) unsigned int*)g,
      (__attribute__((address_space(3))) unsigned int*)l, 16, 0, 0);
}

// Park a 4-reg value in AGPRs (opaque -> not rematerializable/hoistable)
#define PARK_A(x) asm volatile("" : "=a"(x) : "0"(x))
// Zero an AGPR accumulator (fresh park each step)
#define ZERO_A(x) do{ (x) = (f32x4_t){0.f,0.f,0.f,0.f}; asm volatile("" : "+a"(x)); }while(0)
// MFMA fully from AGPR (acc "+a", weights "a"), B (h) from VGPR.
// Leading s_nop 1 covers ALL (VALU/accvgpr_write -> MFMA src read) hazards,
// including compiler-inserted v_movs the hazard recognizer can't see.
#define MFMA_AAV(acc, aw, hv) \
  asm volatile("s_nop 1\n\tv_mfma_f32_16x16x32_f16 %0, %1, %2, %0" \
               : "+a"(acc) : "a"(aw), "v"(hv))
// MFMA-write -> VALU-read fence (>= 11 wait states needed; 16 provided)
#define ACC_FENCE3(a0,a1,a2) \
  asm volatile("s_nop 7\n\ts_nop 7" : "+a"(a0), "+a"(a1), "+a"(a2))

// ---------- X fp32 -> bf16 (dst aliases the xz slot of ws) ----------
__global__ __launch_bounds__(256) void cast_x(const float* __restrict__ X,
                                              unsigned short* __restrict__ XB){
  size_t i = ((size_t)blockIdx.x*256 + threadIdx.x)*8;
  float4 v0 = *(const float4*)&X[i];
  float4 v1 = *(const float4*)&X[i+4];
  ushort4 o0; o0.x=f2bf(v0.x); o0.y=f2bf(v0.y); o0.z=f2bf(v0.z); o0.w=f2bf(v0.w);
  ushort4 o1; o1.x=f2bf(v1.x); o1.y=f2bf(v1.y); o1.z=f2bf(v1.z); o1.w=f2bf(v1.w);
  *(ushort4*)&XB[i]   = o0;
  *(ushort4*)&XB[i+4] = o1;
}

// ---------- Wi{r,z,N} fp32 -> bf16, layout [g][n][k] ----------
__global__ __launch_bounds__(256) void cast_w(const float* __restrict__ Wir,
                                              const float* __restrict__ Wiz,
                                              const float* __restrict__ WiN,
                                              unsigned short* __restrict__ WB){
  size_t i = ((size_t)blockIdx.x*256 + threadIdx.x)*8;
  int g = (int)(i >> 16);
  int rem = (int)(i & 65535);
  const float* W = (g==0) ? Wir : ((g==1) ? Wiz : WiN);
  float4 v0 = *(const float4*)&W[rem];
  float4 v1 = *(const float4*)&W[rem+4];
  ushort4 o0; o0.x=f2bf(v0.x); o0.y=f2bf(v0.y); o0.z=f2bf(v0.z); o0.w=f2bf(v0.w);
  ushort4 o1; o1.x=f2bf(v1.x); o1.y=f2bf(v1.y); o1.z=f2bf(v1.z); o1.w=f2bf(v1.w);
  *(ushort4*)&WB[i]   = o0;
  *(ushort4*)&WB[i+4] = o1;
}

// ---------- input projection: [131072,256] @ WB[g]^T, bf16 MFMA ----------
__global__ __launch_bounds__(256) void proj_kernel(const unsigned short* __restrict__ XB,
                                                   const unsigned short* __restrict__ WB,
                                                   const float* __restrict__ bias,
                                                   const float* __restrict__ bias2,
                                                   unsigned short* __restrict__ dst16,
                                                   float* __restrict__ dst32){
  __shared__ unsigned short As[64][88];
  __shared__ unsigned short Bs[256][88];
  const int tid = threadIdx.x;
  const int m0 = blockIdx.x * 64;
  const int w  = tid >> 6;
  const int l  = tid & 63;
  const int l15 = l & 15;
  const int lq  = l >> 4;

  f32x4_t acc[16];
  #pragma unroll
  for(int i = 0; i < 16; ++i) acc[i] = (f32x4_t){0.f,0.f,0.f,0.f};

  for(int kc = 0; kc < 256; kc += 64){
    #pragma unroll
    for(int p = 0; p < 2; ++p){
      int e = (p*256 + tid)*8;
      int r = e >> 6, k = e & 63;
      *(uint4*)&As[r][k] = *(const uint4*)&XB[(size_t)(m0 + r)*256 + kc + k];
    }
    #pragma unroll
    for(int p = 0; p < 8; ++p){
      int e = (p*256 + tid)*8;
      int n = e >> 6, k = e & 63;
      *(uint4*)&Bs[n][k] = *(const uint4*)&WB[n*256 + kc + k];
    }
    __syncthreads();
    #pragma unroll
    for(int ks = 0; ks < 2; ++ks){
      bf16x8_t a = *(const bf16x8_t*)&As[w*16 + l15][ks*32 + lq*8];
      #pragma unroll
      for(int fc = 0; fc < 16; ++fc){
        bf16x8_t bfr = *(const bf16x8_t*)&Bs[fc*16 + l15][ks*32 + lq*8];
        acc[fc] = __builtin_amdgcn_mfma_f32_16x16x32_bf16(a, bfr, acc[fc], 0, 0, 0);
      }
    }
    __syncthreads();
  }
  #pragma unroll
  for(int fc = 0; fc < 16; ++fc){
    int col = fc*16 + l15;
    float bv = bias[col] + (bias2 ? bias2[col] : 0.f);
    #pragma unroll
    for(int ri = 0; ri < 4; ++ri){
      int row = w*16 + lq*4 + ri;
      size_t idx = (size_t)(m0 + row)*256 + col;
      float v = acc[fc][ri] + bv;
      if(dst32) dst32[idx] = v;
      else      dst16[idx] = f2h(v);
    }
  }
}

// ---------- recurrence: asm-MFMA scan, 4 blocks x 16 batches, 8 waves ------
// D = W (A-AGPR, rows=j) x h^T (B-VGPR, cols=batch), acc in AGPR ("+a").
// R3-R7 established: only inline-asm MFMA reads AGPRs in place; R6 failed on
// unfenced HW hazards. Here every MFMA carries s_nop 1 (VALU->src read) and
// clusters end with s_nop 7x2 (MFMA->VALU read) tied through "+a".
// AGPR: 192 weights + 12 acc = 204; arch ~50 -> fits 256 @ 2 waves/SIMD.
__global__ __attribute__((amdgpu_flat_work_group_size(512,512), amdgpu_waves_per_eu(2,2)))
void scan_kernel(
    const float* __restrict__ Whr, const float* __restrict__ Whz,
    const float* __restrict__ WhN,
    const unsigned short* __restrict__ xr_g,
    const unsigned short* __restrict__ xz_g,
    float* __restrict__ out, float* __restrict__ hlast,
    const float* __restrict__ bhN){
  __shared__ _Float16 hs[2][16][264];                // h, row-major [b][k], 528B rows
  __shared__ __align__(16) _Float16 xr_sh[2][16][256];
  __shared__ __align__(16) _Float16 xz_sh[2][16][256];
  __shared__ __align__(16) float    xn_sh[2][16][256];
  __shared__ float bhn_s[256];

  const int tid  = threadIdx.x;
  const int w    = tid >> 6;      // wave 0..7: owns j in [32w, 32w+32)
  const int l    = tid & 63;
  const int l15  = l & 15;        // = batch b (D col)
  const int rq   = l >> 4;
  const int half = l >> 5;
  const int l31  = l & 31;
  const int b0   = blockIdx.x * 16;

  // ---- load recurrent weights as A-fragments (f16), park in AGPRs ----
  f16x8_t Wr[2][8], Wz[2][8], Wn[2][8];
  #pragma unroll
  for(int jt = 0; jt < 2; ++jt){
    const int j = w*32 + jt*16 + l15;
    #pragma unroll
    for(int kk = 0; kk < 8; ++kk){
      const int ko = j*256 + kk*32 + rq*8;
      float4 a, b;
      a = *(const float4*)&Whr[ko]; b = *(const float4*)&Whr[ko+4];
      Wr[jt][kk] = (f16x8_t){(_Float16)a.x,(_Float16)a.y,(_Float16)a.z,(_Float16)a.w,
                             (_Float16)b.x,(_Float16)b.y,(_Float16)b.z,(_Float16)b.w};
      PARK_A(Wr[jt][kk]);
      a = *(const float4*)&Whz[ko]; b = *(const float4*)&Whz[ko+4];
      Wz[jt][kk] = (f16x8_t){(_Float16)a.x,(_Float16)a.y,(_Float16)a.z,(_Float16)a.w,
                             (_Float16)b.x,(_Float16)b.y,(_Float16)b.z,(_Float16)b.w};
      PARK_A(Wz[jt][kk]);
      a = *(const float4*)&WhN[ko]; b = *(const float4*)&WhN[ko+4];
      Wn[jt][kk] = (f16x8_t){(_Float16)a.x,(_Float16)a.y,(_Float16)a.z,(_Float16)a.w,
                             (_Float16)b.x,(_Float16)b.y,(_Float16)b.z,(_Float16)b.w};
      PARK_A(Wn[jt][kk]);
    }
  }

  for(int i = tid; i < 2*16*264; i += 512) ((_Float16*)hs)[i] = (_Float16)0.f;
  if(tid < 256) bhn_s[tid] = bhN[tid];

  // ---- loop-invariant lane offsets (u32) + uniformly advancing bases ----
  const int bb = 2*w + half;                       // xr/xz staged row (per lane-half)
  const unsigned so_x  = (unsigned)bb*(TH*2) + (unsigned)((l31*16) ^ ((bb & 7) << 4));
  const unsigned so_n0 = (unsigned)(w   )*(TH*4) + (unsigned)((l*16) ^ ((w        & 7) << 4));
  const unsigned so_n1 = (unsigned)(w+8 )*(TH*4) + (unsigned)((l*16) ^ (((w+8)    & 7) << 4));
  const unsigned st_off = (unsigned)l15*TH + (unsigned)(w*32 + rq*4); // elems
  const char* xr_t = (const char*)(xr_g + (size_t)b0*TH);
  const char* xz_t = (const char*)(xz_g + (size_t)b0*TH);
  float*      out_t = out + (size_t)b0*TH;

  // ---- stage t=0 into buf 0 ----
  stage16(xr_t + so_x, &xr_sh[0][2*w][0]);
  stage16(xz_t + so_x, &xz_sh[0][2*w][0]);
  stage16((const char*)out_t + so_n0, &xn_sh[0][w][0]);
  stage16((const char*)out_t + so_n1, &xn_sh[0][w+8][0]);
  __syncthreads();

  const int swz = (l15 & 7) << 4;

  for(int t = 0; t < T_SZ; ++t){
    const int pb = t & 1;
    // ---- stage t+1 into buf pb^1 (async; drained by end-of-step barrier) ----
    if(t + 1 < T_SZ){
      stage16(xr_t + 512 + so_x, &xr_sh[pb^1][2*w][0]);
      stage16(xz_t + 512 + so_x, &xz_sh[pb^1][2*w][0]);
      stage16((const char*)out_t + 1024 + so_n0, &xn_sh[pb^1][w][0]);
      stage16((const char*)out_t + 1024 + so_n1, &xn_sh[pb^1][w+8][0]);
    }

    // ---- per j-half: MFMA cluster (AGPR) -> fence -> epilogue ----
    #pragma unroll
    for(int cb = 0; cb < 2; ++cb){
      f32x4_t ar, az, an;
      ZERO_A(ar); ZERO_A(az); ZERO_A(an);
      #pragma unroll
      for(int kk = 0; kk < 8; ++kk){
        f16x8_t hq = *(const f16x8_t*)&hs[pb][l15][kk*32 + rq*8];
        if(cb == 0){
          MFMA_AAV(ar, Wr[0][kk], hq);
          MFMA_AAV(az, Wz[0][kk], hq);
          MFMA_AAV(an, Wn[0][kk], hq);
        }else{
          MFMA_AAV(ar, Wr[1][kk], hq);
          MFMA_AAV(az, Wz[1][kk], hq);
          MFMA_AAV(an, Wn[1][kk], hq);
        }
      }
      ACC_FENCE3(ar, az, an);

      const int jb = w*32 + cb*16 + rq*4;
      ushort4 xr4 = *(const ushort4*)((const char*)xr_sh + pb*8192  + l15*512  + ((jb*2) ^ swz));
      ushort4 xz4 = *(const ushort4*)((const char*)xz_sh + pb*8192  + l15*512  + ((jb*2) ^ swz));
      float4  xn4 = *(const float4*) ((const char*)xn_sh + pb*16384 + l15*1024 + ((jb*4) ^ swz));
      ushort4 hp4 = *(const ushort4*)((const char*)hs    + pb*8448  + l15*528  + jb*2);
      float4  bn4 = *(const float4*)&bhn_s[jb];
      const unsigned short* xrp = (const unsigned short*)&xr4;
      const unsigned short* xzp = (const unsigned short*)&xz4;
      const unsigned short* hpp = (const unsigned short*)&hp4;
      const float* xnp = (const float*)&xn4;
      const float* bnp = (const float*)&bn4;
      float4 hn4; float* hnp = (float*)&hn4;
      #pragma unroll
      for(int ri = 0; ri < 4; ++ri){
        float rg = sigmoidf_(ar[ri] + h2f(xrp[ri]));
        float zg = sigmoidf_(az[ri] + h2f(xzp[ri]));
        float ng = tanhf_(xnp[ri] + rg*(an[ri] + bnp[ri]));
        float hp = h2f(hpp[ri]);
        hnp[ri] = ng + zg*(hp - ng);
      }
      *(float4*)(out_t + st_off + cb*16) = hn4;
      ushort4 hw; hw.x = f2h(hnp[0]); hw.y = f2h(hnp[1]); hw.z = f2h(hnp[2]); hw.w = f2h(hnp[3]);
      *(ushort4*)((char*)hs + (pb^1)*8448 + l15*528 + jb*2) = hw;
    }
    xr_t += 512; xz_t += 512; out_t += 256;
    __syncthreads();
  }

  // final h lives in hs[0] (t=2047 wrote buf 0)
  #pragma unroll
  for(int cb = 0; cb < 2; ++cb){
    const int jb = w*32 + cb*16 + rq*4;
    ushort4 hf = *(const ushort4*)((const char*)hs + l15*528 + jb*2);
    float4 o; o.x = h2f(hf.x); o.y = h2f(hf.y); o.z = h2f(hf.z); o.w = h2f(hf.w);
    *(float4*)&hlast[(size_t)(b0 + l15)*H_SZ + jb] = o;
  }
}

extern "C" void kernel_launch(void* const* d_in, const int* in_sizes, int n_in,
                              void* d_out, int out_size, void* d_ws, size_t ws_size,
                              hipStream_t stream){
  const float* X   = (const float*)d_in[0];
  const float* Wir = (const float*)d_in[1];
  const float* bir = (const float*)d_in[2];
  const float* Whr = (const float*)d_in[3];
  const float* bhr = (const float*)d_in[4];
  const float* Wiz = (const float*)d_in[5];
  const float* biz = (const float*)d_in[6];
  const float* Whz = (const float*)d_in[7];
  const float* bhz = (const float*)d_in[8];
  const float* WiN = (const float*)d_in[9];
  const float* biN = (const float*)d_in[10];
  const float* WhN = (const float*)d_in[11];
  const float* bhN = (const float*)d_in[12];

  float* out   = (float*)d_out;
  float* hlast = out + (size_t)B_SZ*TH;

  unsigned char* ws = (unsigned char*)d_ws;
  const size_t XN = (size_t)B_SZ*TH;                 // 33,554,432
  unsigned short* xr = (unsigned short*)ws;          // 67.1 MB f16
  unsigned short* xz = (unsigned short*)(ws + XN*2); // 67.1 MB (bf16 X first, xz after)
  unsigned short* WB = (unsigned short*)(ws + XN*4); // 384 KB bf16 input weights
  unsigned short* XB = xz;                           // bf16 X aliases the xz slot

  cast_w<<<96, 256, 0, stream>>>(Wir, Wiz, WiN, WB);
  cast_x<<<16384, 256, 0, stream>>>(X, XB);
  proj_kernel<<<2048, 256, 0, stream>>>(XB, WB,           bir, bhr,     xr, nullptr);
  proj_kernel<<<2048, 256, 0, stream>>>(XB, WB + 2*65536, biN, nullptr, nullptr, out);
  // z LAST: writes xz in place over XB (block reads whole A-tile before epilogue)
  proj_kernel<<<2048, 256, 0, stream>>>(XB, WB + 65536,   biz, bhz,     xz, nullptr);
  scan_kernel<<<4, 512, 0, stream>>>(Whr, Whz, WhN, xr, xz, out, hlast, bhN);
}

// Round 9
// 3200.333 us; speedup vs baseline: 2.6701x; 2.6701x over previous
//
#include <hip/hip_runtime.h>
#include <stdint.h>

#define B_SZ 64
#define T_SZ 2048
#define H_SZ 256
#define TH   (T_SZ * H_SZ)

typedef __attribute__((ext_vector_type(8))) short bf16x8_t;
typedef __attribute__((ext_vector_type(4))) float f32x4_t;
typedef __attribute__((ext_vector_type(2))) _Float16 half2_t;

#if defined(__has_builtin)
#if __has_builtin(__builtin_amdgcn_fdot2)
#define HAVE_FDOT2 1
#endif
#endif
#ifndef HAVE_FDOT2
#define HAVE_FDOT2 0
#endif

static __device__ __forceinline__ unsigned short f2bf(float f){
  unsigned int u = __float_as_uint(f);
  return (unsigned short)((u + 0x7fffu + ((u >> 16) & 1u)) >> 16);
}
static __device__ __forceinline__ unsigned short f2h(float f){
  return __builtin_bit_cast(unsigned short, (_Float16)f);
}
static __device__ __forceinline__ float h2f(unsigned short h){
  return (float)__builtin_bit_cast(_Float16, h);
}
static __device__ __forceinline__ unsigned int pkh(float a, float b){
  return (unsigned int)f2h(a) | ((unsigned int)f2h(b) << 16);
}
static __device__ __forceinline__ float dot2acc(unsigned int wv, unsigned int hv, float acc){
#if HAVE_FDOT2
  return __builtin_amdgcn_fdot2(__builtin_bit_cast(half2_t, wv),
                                __builtin_bit_cast(half2_t, hv), acc, false);
#else
  half2_t w2 = __builtin_bit_cast(half2_t, wv);
  half2_t h2 = __builtin_bit_cast(half2_t, hv);
  acc = fmaf((float)w2.x, (float)h2.x, acc);
  acc = fmaf((float)w2.y, (float)h2.y, acc);
  return acc;
#endif
}
static __device__ __forceinline__ float sigmoidf_(float x){
  return 1.f / (1.f + __expf(-x));
}
static __device__ __forceinline__ float tanhf_(float x){
  float e = __expf(-2.f * fabsf(x));
  float t = (1.f - e) / (1.f + e);
  return copysignf(t, x);
}
// global -> LDS async DMA: per-lane global src, LDS dest = uniform base + lane*16
static __device__ __forceinline__ void stage16(const void* g, void* l){
  __builtin_amdgcn_global_load_lds(
      (const __attribute__((address_space(1))) unsigned int*)g,
      (__attribute__((address_space(3))) unsigned int*)l, 16, 0, 0);
}

// ---------- pack recurrent weights: f16 pairs along k ----------
// WP[g][q][j] : uint4 = k-values 8q..8q+7 of row j of gate g (lo half = even k)
__global__ __launch_bounds__(256) void prep_pack(const float* __restrict__ Whr,
                                                 const float* __restrict__ Whz,
                                                 const float* __restrict__ WhN,
                                                 uint4* __restrict__ WP){
  const int g = blockIdx.x;
  const int j = threadIdx.x;
  const float* W = (g == 0) ? Whr : ((g == 1) ? Whz : WhN);
  #pragma unroll 4
  for(int q = 0; q < 32; ++q){
    float4 a = *(const float4*)&W[j*256 + q*8];
    float4 b = *(const float4*)&W[j*256 + q*8 + 4];
    uint4 o;
    o.x = pkh(a.x, a.y);
    o.y = pkh(a.z, a.w);
    o.z = pkh(b.x, b.y);
    o.w = pkh(b.z, b.w);
    WP[(g*32 + q)*256 + j] = o;
  }
}

// ---------- X fp32 -> bf16 (dst aliases the xz slot of ws) ----------
__global__ __launch_bounds__(256) void cast_x(const float* __restrict__ X,
                                              unsigned short* __restrict__ XB){
  size_t i = ((size_t)blockIdx.x*256 + threadIdx.x)*8;
  float4 v0 = *(const float4*)&X[i];
  float4 v1 = *(const float4*)&X[i+4];
  ushort4 o0; o0.x=f2bf(v0.x); o0.y=f2bf(v0.y); o0.z=f2bf(v0.z); o0.w=f2bf(v0.w);
  ushort4 o1; o1.x=f2bf(v1.x); o1.y=f2bf(v1.y); o1.z=f2bf(v1.z); o1.w=f2bf(v1.w);
  *(ushort4*)&XB[i]   = o0;
  *(ushort4*)&XB[i+4] = o1;
}

// ---------- Wi{r,z,N} fp32 -> bf16, layout [g][n][k] ----------
__global__ __launch_bounds__(256) void cast_w(const float* __restrict__ Wir,
                                              const float* __restrict__ Wiz,
                                              const float* __restrict__ WiN,
                                              unsigned short* __restrict__ WB){
  size_t i = ((size_t)blockIdx.x*256 + threadIdx.x)*8;
  int g = (int)(i >> 16);
  int rem = (int)(i & 65535);
  const float* W = (g==0) ? Wir : ((g==1) ? Wiz : WiN);
  float4 v0 = *(const float4*)&W[rem];
  float4 v1 = *(const float4*)&W[rem+4];
  ushort4 o0; o0.x=f2bf(v0.x); o0.y=f2bf(v0.y); o0.z=f2bf(v0.z); o0.w=f2bf(v0.w);
  ushort4 o1; o1.x=f2bf(v1.x); o1.y=f2bf(v1.y); o1.z=f2bf(v1.z); o1.w=f2bf(v1.w);
  *(ushort4*)&WB[i]   = o0;
  *(ushort4*)&WB[i+4] = o1;
}

// ---------- input projection: [131072,256] @ WB[g]^T, bf16 MFMA ----------
__global__ __launch_bounds__(256) void proj_kernel(const unsigned short* __restrict__ XB,
                                                   const unsigned short* __restrict__ WB,
                                                   const float* __restrict__ bias,
                                                   const float* __restrict__ bias2,
                                                   unsigned short* __restrict__ dst16,
                                                   float* __restrict__ dst32){
  __shared__ unsigned short As[64][88];
  __shared__ unsigned short Bs[256][88];
  const int tid = threadIdx.x;
  const int m0 = blockIdx.x * 64;
  const int w  = tid >> 6;
  const int l  = tid & 63;
  const int l15 = l & 15;
  const int lq  = l >> 4;

  f32x4_t acc[16];
  #pragma unroll
  for(int i = 0; i < 16; ++i) acc[i] = (f32x4_t){0.f,0.f,0.f,0.f};

  for(int kc = 0; kc < 256; kc += 64){
    #pragma unroll
    for(int p = 0; p < 2; ++p){
      int e = (p*256 + tid)*8;
      int r = e >> 6, k = e & 63;
      *(uint4*)&As[r][k] = *(const uint4*)&XB[(size_t)(m0 + r)*256 + kc + k];
    }
    #pragma unroll
    for(int p = 0; p < 8; ++p){
      int e = (p*256 + tid)*8;
      int n = e >> 6, k = e & 63;
      *(uint4*)&Bs[n][k] = *(const uint4*)&WB[n*256 + kc + k];
    }
    __syncthreads();
    #pragma unroll
    for(int ks = 0; ks < 2; ++ks){
      bf16x8_t a = *(const bf16x8_t*)&As[w*16 + l15][ks*32 + lq*8];
      #pragma unroll
      for(int fc = 0; fc < 16; ++fc){
        bf16x8_t bfr = *(const bf16x8_t*)&Bs[fc*16 + l15][ks*32 + lq*8];
        acc[fc] = __builtin_amdgcn_mfma_f32_16x16x32_bf16(a, bfr, acc[fc], 0, 0, 0);
      }
    }
    __syncthreads();
  }
  #pragma unroll
  for(int fc = 0; fc < 16; ++fc){
    int col = fc*16 + l15;
    float bv = bias[col] + (bias2 ? bias2[col] : 0.f);
    #pragma unroll
    for(int ri = 0; ri < 4; ++ri){
      int row = w*16 + lq*4 + ri;
      size_t idx = (size_t)(m0 + row)*256 + col;
      float v = acc[fc][ri] + bv;
      if(dst32) dst32[idx] = v;
      else      dst16[idx] = f2h(v);
    }
  }
}

// ---------- recurrence: dot2 scan, 1 block per batch, 64 blocks ----------
// thread (g=tid>>8, j=tid&255) computes gate g's dot for output j.
// Weight budget honest this time: 22 uint4 resident (88 VGPR, total demand
// ~120 <= the allocator's 128 comfort zone) + 10 uint4 in LDS (120 KB).
// h f16-packed in LDS, broadcast reads. x staged 2 steps at a time via
// global_load_lds. Balanced epilogue: r/z waves own their sigmoids.
#define QRES 22
__global__ __launch_bounds__(768) void scan_kernel(
    const uint4* __restrict__ WP,
    const unsigned short* __restrict__ xr_g,
    const unsigned short* __restrict__ xz_g,
    float* __restrict__ out, float* __restrict__ hlast,
    const float* __restrict__ bhN){
  __shared__ uint4 WL[3][32-QRES][256];                  // 120 KB weights q>=QRES
  __shared__ __align__(16) unsigned int hs[128];         // h as packed f16 pairs
  __shared__ __align__(16) _Float16 xr_sh[2][512];       // 2 steps per buffer
  __shared__ __align__(16) _Float16 xz_sh[2][512];
  __shared__ __align__(16) float    xn_sh[2][512];
  __shared__ float pr[256], pz[256];

  const int tid = threadIdx.x;
  const int g = tid >> 8;
  const int j = tid & 255;
  const int w = tid >> 6;        // wave 0..11
  const int l = tid & 63;
  const int b = blockIdx.x;

  // resident weights q = 0..QRES-1
  uint4 wreg[QRES];
  #pragma unroll
  for(int q = 0; q < QRES; ++q) wreg[q] = WP[(g*32 + q)*256 + j];
  // LDS weights q = QRES..31
  for(int i = tid; i < 3*(32-QRES)*256; i += 768){
    int gg = i / ((32-QRES)*256);
    int rem = i - gg*((32-QRES)*256);
    int qq = rem >> 8, jj = rem & 255;
    WL[gg][qq][jj] = WP[(gg*32 + QRES + qq)*256 + jj];
  }
  if(tid < 128) hs[tid] = 0u;
  const float bn = (g == 2) ? bhN[j] : 0.f;
  float hp = 0.f;

  const char* xr_b = (const char*)(xr_g + (size_t)b*TH);
  const char* xz_b = (const char*)(xz_g + (size_t)b*TH);
  const char* xn_b = (const char*)(out + (size_t)b*TH);   // xn fp32 lives in d_out
  float* out_b = out + (size_t)b*TH;

  // stage steps 0,1 into buffer 0 (1 KB per DMA wave)
  if(w == 0)      stage16(xr_b + l*16, &xr_sh[0][0]);
  else if(w == 1) stage16(xz_b + l*16, &xz_sh[0][0]);
  else if(w == 2) stage16(xn_b + l*16, &xn_sh[0][0]);
  else if(w == 3) stage16(xn_b + 1024 + l*16, &xn_sh[0][256]);
  __syncthreads();   // compiler drains vmcnt+lgkmcnt before s_barrier

  for(int t = 0; t < T_SZ; ++t){
    const int pb = (t >> 1) & 1;
    // every other step: stage steps t+2, t+3 into the other buffer
    if((t & 1) == 0 && t + 2 < T_SZ){
      const int nb = pb ^ 1;
      if(w == 0)      stage16(xr_b + (t+2)*512  + l*16, &xr_sh[nb][0]);
      else if(w == 1) stage16(xz_b + (t+2)*512  + l*16, &xz_sh[nb][0]);
      else if(w == 2) stage16(xn_b + (t+2)*1024 + l*16, &xn_sh[nb][0]);
      else if(w == 3) stage16(xn_b + (t+2)*1024 + 1024 + l*16, &xn_sh[nb][256]);
    }

    // ---- 256-wide dot in f16 pairs: 4 parallel accumulator chains ----
    const uint4* hs4 = (const uint4*)hs;
    float a0 = 0.f, a1 = 0.f, a2 = 0.f, a3 = 0.f;
    #pragma unroll
    for(int q = 0; q < QRES; ++q){
      uint4 hq = hs4[q];                  // wave-uniform broadcast read
      a0 = dot2acc(wreg[q].x, hq.x, a0);
      a1 = dot2acc(wreg[q].y, hq.y, a1);
      a2 = dot2acc(wreg[q].z, hq.z, a2);
      a3 = dot2acc(wreg[q].w, hq.w, a3);
    }
    #pragma unroll
    for(int q = 0; q < 32-QRES; ++q){
      uint4 wq = WL[g][q][j];
      uint4 hq = hs4[QRES + q];
      a0 = dot2acc(wq.x, hq.x, a0);
      a1 = dot2acc(wq.y, hq.y, a1);
      a2 = dot2acc(wq.z, hq.z, a2);
      a3 = dot2acc(wq.w, hq.w, a3);
    }
    const float s = (a0 + a1) + (a2 + a3);

    const int to = (t & 1) << 8;
    if(g == 0)      pr[j] = sigmoidf_(s + (float)xr_sh[pb][to + j]);
    else if(g == 1) pz[j] = sigmoidf_(s + (float)xz_sh[pb][to + j]);
    __syncthreads();   // pr/pz visible; all hs reads of step t done

    if(g == 2){
      float xn = xn_sh[pb][to + j];
      float n  = tanhf_(xn + pr[j]*(s + bn));
      float z  = pz[j];
      float hn = n + z*(hp - n);
      hp = hn;
      out_b[t*256 + j] = hn;
      ((_Float16*)hs)[j] = (_Float16)hn;   // h for step t+1 (f16-packed)
    }
    __syncthreads();   // h visible before next step's dots
  }
  if(g == 2) hlast[b*256 + j] = hp;
}

extern "C" void kernel_launch(void* const* d_in, const int* in_sizes, int n_in,
                              void* d_out, int out_size, void* d_ws, size_t ws_size,
                              hipStream_t stream){
  const float* X   = (const float*)d_in[0];
  const float* Wir = (const float*)d_in[1];
  const float* bir = (const float*)d_in[2];
  const float* Whr = (const float*)d_in[3];
  const float* bhr = (const float*)d_in[4];
  const float* Wiz = (const float*)d_in[5];
  const float* biz = (const float*)d_in[6];
  const float* Whz = (const float*)d_in[7];
  const float* bhz = (const float*)d_in[8];
  const float* WiN = (const float*)d_in[9];
  const float* biN = (const float*)d_in[10];
  const float* WhN = (const float*)d_in[11];
  const float* bhN = (const float*)d_in[12];

  float* out   = (float*)d_out;
  float* hlast = out + (size_t)B_SZ*TH;

  unsigned char* ws = (unsigned char*)d_ws;
  const size_t XN = (size_t)B_SZ*TH;                  // 33,554,432
  unsigned short* xr = (unsigned short*)ws;           // 67.1 MB f16
  unsigned short* xz = (unsigned short*)(ws + XN*2);  // 67.1 MB (bf16 X first, xz after)
  unsigned short* WB = (unsigned short*)(ws + XN*4);  // 384 KB bf16 input weights
  uint4*          WP = (uint4*)(ws + XN*4 + 393216);  // 384 KB packed recurrent weights
  unsigned short* XB = xz;                            // bf16 X aliases the xz slot

  cast_w<<<96, 256, 0, stream>>>(Wir, Wiz, WiN, WB);
  prep_pack<<<3, 256, 0, stream>>>(Whr, Whz, WhN, WP);
  cast_x<<<16384, 256, 0, stream>>>(X, XB);
  // r-gate: fold bhr; n-gate: fp32 xn -> d_out (bhN applied in scan)
  proj_kernel<<<2048, 256, 0, stream>>>(XB, WB,           bir, bhr,     xr, nullptr);
  proj_kernel<<<2048, 256, 0, stream>>>(XB, WB + 2*65536, biN, nullptr, nullptr, out);
  // z LAST: writes xz in place over XB (block reads whole A-tile before epilogue)
  proj_kernel<<<2048, 256, 0, stream>>>(XB, WB + 65536,   biz, bhz,     xz, nullptr);
  scan_kernel<<<64, 768, 0, stream>>>(WP, xr, xz, out, hlast, bhN);
}